// Round 3
// baseline (646.836 us; speedup 1.0000x reference)
//
#include <hip/hip_runtime.h>
#include <hip/hip_fp16.h>

#define B_ 4096
#define T_ 64
#define NROWS (B_*T_)   // 262144

typedef _Float16 f16x8 __attribute__((ext_vector_type(8)));
typedef float    f32x4 __attribute__((ext_vector_type(4)));

__device__ __forceinline__ float gelu_f(float x){
    return 0.5f * x * (1.0f + erff(x * 0.70710678118654752f));
}

// ---------- staged-weight pipeline: [128][128] f32 -> 16 VGPRs f16 -> 4x ds_write_b128
// Final layout identical to R1's stage_wt: WT[cc][k] at byte cc*256 + ((2k) ^ ((cc&7)<<4))
struct SW { f16x8 v[4]; };

__device__ __forceinline__ void sw_load(SW& s, const float* __restrict__ w, int tid){
    const int l = tid & 63, kk0 = (tid >> 6) & 7;
#pragma unroll
    for (int hh = 0; hh < 2; hh++){
        const int cc = l + hh * 64;
#pragma unroll
        for (int j = 0; j < 2; j++){
            const int kk = kk0 + j * 8;
            const float* src = w + kk * 8 * 128 + cc;   // 64 lanes: 256B coalesced
            f16x8 t;
#pragma unroll
            for (int m = 0; m < 8; m++) t[m] = (_Float16)src[m * 128];
            s.v[hh * 2 + j] = t;
        }
    }
}

__device__ __forceinline__ void sw_write(const SW& s, unsigned short* buf, int tid){
    const int l = tid & 63, kk0 = (tid >> 6) & 7;
#pragma unroll
    for (int hh = 0; hh < 2; hh++){
        const int cc = l + hh * 64;
        char* dst = (char*)buf + cc * 256;
        const int swz = (cc & 7) << 4;
#pragma unroll
        for (int j = 0; j < 2; j++){
            const int kk = kk0 + j * 8;
            *(f16x8*)(dst + ((kk * 16) ^ swz)) = s.v[hh * 2 + j];
        }
    }
}

// ---------- stage W2 (128 x 2) transposed+padded to WT[16][128] (rows 2..15 zero) — R1 exact
__device__ __forceinline__ void stage_w2(const float* __restrict__ w,
                                         unsigned short* buf, int tid){
    for (int idx = tid; idx < 2048; idx += 512){
        int r = idx >> 7, k = idx & 127;
        float v = (r < 2) ? w[k * 2 + r] : 0.f;
        int byte = r * 256 + ((k << 1) ^ ((r & 7) << 4));
        *(_Float16*)((char*)buf + byte) = (_Float16)v;
    }
}

// ---------- input rows -> f16 A-fragments (K=128 -> 4 frags)
__device__ __forceinline__ void load_in(f16x8* a, const float* __restrict__ p, int g){
#pragma unroll
    for (int ks = 0; ks < 4; ks++){
        const float* q = p + ks * 32 + g * 8;
        float4 v0 = *(const float4*)q, v1 = *(const float4*)(q + 4);
        f16x8 t;
        t[0]=(_Float16)v0.x; t[1]=(_Float16)v0.y; t[2]=(_Float16)v0.z; t[3]=(_Float16)v0.w;
        t[4]=(_Float16)v1.x; t[5]=(_Float16)v1.y; t[6]=(_Float16)v1.z; t[7]=(_Float16)v1.w;
        a[ks] = t;
    }
}

// ---------- A-fragments from wave-private abuf tile [16][128] f16
__device__ __forceinline__ void load_a(f16x8* a, const char* ab, int c, int g){
    const int rswz = (c & 7) << 4;
    const char* rp = ab + c * 256;
#pragma unroll
    for (int ks = 0; ks < 4; ks++)
        a[ks] = *(const f16x8*)(rp + ((ks * 64 + g * 16) ^ rswz));
}

// ---------- full 8-tile MFMA vs staged weights (K=128, row stride 256B)
__device__ __forceinline__ void mfma_tile(f32x4* acc, const f16x8* a,
                                          const unsigned short* wb, int c, int g){
#pragma unroll
    for (int n = 0; n < 8; n++){
        const int r = n * 16 + c;
        const char* rp = (const char*)wb + r * 256;
        const int swz = (r & 7) << 4;
#pragma unroll
        for (int ks = 0; ks < 4; ks++){
            f16x8 b = *(const f16x8*)(rp + ((ks * 64 + g * 16) ^ swz));
            acc[n] = __builtin_amdgcn_mfma_f32_16x16x32_f16(a[ks], b, acc[n], 0, 0, 0);
        }
    }
}

// ======================= stats kernel ======================================
__global__ void k_stats(const int* __restrict__ mask, const int* __restrict__ labels,
                        float* __restrict__ ws){
    int t = blockIdx.x, tid = threadIdx.x;
    float c0 = 0.f, c1 = 0.f;
    for (int b = tid; b < B_; b += 256){
        if (mask[b * T_ + t]){
            if (labels[b] == 1) c1 += 1.f; else c0 += 1.f;
        }
    }
    for (int m = 1; m < 64; m <<= 1){ c0 += __shfl_xor(c0, m); c1 += __shfl_xor(c1, m); }
    __shared__ float sh[8];
    int w = tid >> 6, l = tid & 63;
    if (l == 0){ sh[w] = c0; sh[4 + w] = c1; }
    __syncthreads();
    if (tid == 0){
        float a0 = sh[0] + sh[1] + sh[2] + sh[3];
        float a1 = sh[4] + sh[5] + sh[6] + sh[7];
        float tot = a0 + a1;
        float d = fmaxf(tot, 1.f);
        float p0 = a0 / d, p1 = a1 / d;
        float ent = -(p0 * logf(p0 + 1e-8f) + p1 * logf(p1 + 1e-8f));
        ws[t] = ent;
        ws[64 + t] = (tot >= 2.f) ? 1.f : 0.f;
        ws[128 + t] = tot;
    }
}

// ======================= main fused kernel =================================
// LDS: wbuf 32K + abuf 32K + w2c 4K + w2j 4K + sb 6.2K = 78.2 KB -> 2 blocks/CU.
__global__ __launch_bounds__(512, 4) void k_main(
    const float* __restrict__ xc, const float* __restrict__ xs,
    const int* __restrict__ labels, const int* __restrict__ mask,
    const float* __restrict__ ce_w1, const float* __restrict__ ce_b1,
    const float* __restrict__ ce_w2, const float* __restrict__ ce_b2,
    const float* __restrict__ se_w1, const float* __restrict__ se_b1,
    const float* __restrict__ se_w2, const float* __restrict__ se_b2,
    const float* __restrict__ cd_g,  const float* __restrict__ cd_bt,
    const float* __restrict__ cd_w1, const float* __restrict__ cd_b1,
    const float* __restrict__ cd_w2, const float* __restrict__ cd_b2,
    const float* __restrict__ jd_g,  const float* __restrict__ jd_bt,
    const float* __restrict__ jd_w1, const float* __restrict__ jd_b1,
    const float* __restrict__ jd_w2, const float* __restrict__ jd_b2,
    float* __restrict__ ws, float* __restrict__ out)
{
    __shared__ __align__(16) unsigned short wbuf[128 * 128];    // 32 KB
    __shared__ __align__(16) unsigned short abuf[8 * 16 * 128]; // 32 KB
    __shared__ __align__(16) unsigned short w2c[16 * 128];      // 4 KB
    __shared__ __align__(16) unsigned short w2j[16 * 128];      // 4 KB
    __shared__ float sb[1540];
    // sb: 0 ce_b1 |128 ce_b2 |256 se_b1 |384 se_b2 |512 cd_g |640 cd_b |768 cd_b1
    //     896 jd_b1 |1024 jd_g[256] |1280 jd_b[256] |1536 cd_b2[2] |1538 jd_b2[2]

    const int tid = threadIdx.x;
    const int wave = tid >> 6, lane = tid & 63;
    const int c = lane & 15, g = lane >> 4;
    const int wrow0 = blockIdx.x * 128 + wave * 16;
    char* const ab = (char*)abuf + wave * 4096;
    const int lab = labels[(wrow0 + g * 4) >> 6];

    SW s;
    f16x8 a4[4];
    f32x4 accC[8], accS[8], accW2[8];

    // ---------------- region 0: stage ce_w1 + w2 pads + sb -----------------
    sw_load(s, ce_w1, tid);
    f16x8 aC[4];
    load_in(aC, xc + (wrow0 + c) * 128, g);
    stage_w2(cd_w2, w2c, tid);
    stage_w2(jd_w2, w2j, tid);
    if (tid < 128){
        sb[tid] = ce_b1[tid];       sb[128 + tid] = ce_b2[tid];
        sb[256 + tid] = se_b1[tid]; sb[384 + tid] = se_b2[tid];
        sb[512 + tid] = cd_g[tid];  sb[640 + tid] = cd_bt[tid];
        sb[768 + tid] = cd_b1[tid]; sb[896 + tid] = jd_b1[tid];
    } else if (tid < 384){
        int i = tid - 128; sb[1024 + i] = jd_g[i]; sb[1280 + i] = jd_bt[i];
    } else if (tid < 386){
        int i = tid - 384; sb[1536 + i] = cd_b2[i]; sb[1538 + i] = jd_b2[i];
    }
    sw_write(s, wbuf, tid);
    __syncthreads();                                            // B1: ce_w1 ready

    // ---------------- enc1 causal (wbuf = ce_w1) ---------------------------
    sw_load(s, ce_w2, tid);
    {
        f32x4 acc[8];
#pragma unroll
        for (int n = 0; n < 8; n++) acc[n] = (f32x4){0.f,0.f,0.f,0.f};
        mfma_tile(acc, aC, wbuf, c, g);
#pragma unroll
        for (int n = 0; n < 8; n++){
            const int col = n * 16 + c;
            float bi = sb[col];
#pragma unroll
            for (int rr = 0; rr < 4; rr++){
                float v = gelu_f(acc[n][rr] + bi);
                int row = g * 4 + rr;
                *(_Float16*)(ab + row * 256 + ((col << 1) ^ ((row & 7) << 4))) = (_Float16)v;
            }
        }
    }
    __syncthreads();                                            // B2
    sw_write(s, wbuf, tid);
    __syncthreads();                                            // B3: ce_w2 ready

    // ---------------- enc2 causal -> accC ----------------------------------
    sw_load(s, se_w1, tid);
    f16x8 aS[4];
    load_in(aS, xs + (wrow0 + c) * 128, g);
    {
        load_a(a4, ab, c, g);
#pragma unroll
        for (int n = 0; n < 8; n++) accC[n] = (f32x4){0.f,0.f,0.f,0.f};
        mfma_tile(accC, a4, wbuf, c, g);
#pragma unroll
        for (int n = 0; n < 8; n++){
            float bi = sb[128 + n * 16 + c];
#pragma unroll
            for (int rr = 0; rr < 4; rr++) accC[n][rr] += bi;
        }
    }
    __syncthreads();                                            // B4
    sw_write(s, wbuf, tid);
    __syncthreads();                                            // B5: se_w1 ready

    // ---------------- enc1 spurious ----------------------------------------
    sw_load(s, se_w2, tid);
    {
        f32x4 acc[8];
#pragma unroll
        for (int n = 0; n < 8; n++) acc[n] = (f32x4){0.f,0.f,0.f,0.f};
        mfma_tile(acc, aS, wbuf, c, g);
#pragma unroll
        for (int n = 0; n < 8; n++){
            const int col = n * 16 + c;
            float bi = sb[256 + col];
#pragma unroll
            for (int rr = 0; rr < 4; rr++){
                float v = gelu_f(acc[n][rr] + bi);
                int row = g * 4 + rr;
                *(_Float16*)(ab + row * 256 + ((col << 1) ^ ((row & 7) << 4))) = (_Float16)v;
            }
        }
    }
    __syncthreads();                                            // B6
    sw_write(s, wbuf, tid);
    __syncthreads();                                            // B7: se_w2 ready

    // ---------------- enc2 spurious -> accS --------------------------------
    sw_load(s, cd_w1, tid);
    {
        load_a(a4, ab, c, g);
#pragma unroll
        for (int n = 0; n < 8; n++) accS[n] = (f32x4){0.f,0.f,0.f,0.f};
        mfma_tile(accS, a4, wbuf, c, g);
#pragma unroll
        for (int n = 0; n < 8; n++){
            float bi = sb[384 + n * 16 + c];
#pragma unroll
            for (int rr = 0; rr < 4; rr++) accS[n][rr] += bi;
        }
    }
    __syncthreads();                                            // B8
    sw_write(s, wbuf, tid);
    __syncthreads();                                            // B9: cd_w1 ready

    // ---------------- causal decoder: LN -> hidden -> logits (R1 path) -----
    sw_load(s, jd_w1 + 128 * 128, tid);   // prefetch jd_w1 B-half (s_rep dims)
    float ceC[4], ceJ[4];
    {
        float s0[4]={0,0,0,0}, s1[4]={0,0,0,0};
#pragma unroll
        for (int n = 0; n < 8; n++)
#pragma unroll
            for (int rr = 0; rr < 4; rr++){ float v = accC[n][rr]; s0[rr]+=v; s1[rr]+=v*v; }
#pragma unroll
        for (int rr = 0; rr < 4; rr++)
#pragma unroll
            for (int m = 1; m < 16; m <<= 1){ s0[rr]+=__shfl_xor(s0[rr],m); s1[rr]+=__shfl_xor(s1[rr],m); }
        float mean[4], rstd[4];
#pragma unroll
        for (int rr = 0; rr < 4; rr++){
            mean[rr] = s0[rr] * (1.f/128.f);
            rstd[rr] = rsqrtf(s1[rr]*(1.f/128.f) - mean[rr]*mean[rr] + 1e-5f);
        }
#pragma unroll
        for (int n = 0; n < 8; n++){
            const int col = n * 16 + c;
#pragma unroll
            for (int rr = 0; rr < 4; rr++){
                float y = (accC[n][rr]-mean[rr])*rstd[rr]*sb[512+col] + sb[640+col];
                int row = g * 4 + rr;
                *(_Float16*)(ab + row * 256 + ((col << 1) ^ ((row & 7) << 4))) = (_Float16)y;
            }
        }
    }
    __syncthreads();                                            // B9a: LN tile ready
    {
        load_a(a4, ab, c, g);
        // hidden per output-tile n (t = 1 acc), gelu -> overwrite ab
#pragma unroll
        for (int n = 0; n < 8; n++){
            const int r = n * 16 + c;
            const char* rp = (const char*)wbuf + r * 256;
            const int swz = (r & 7) << 4;
            f32x4 t = (f32x4){0.f,0.f,0.f,0.f};
#pragma unroll
            for (int ks = 0; ks < 4; ks++){
                f16x8 b = *(const f16x8*)(rp + ((ks * 64 + g * 16) ^ swz));
                t = __builtin_amdgcn_mfma_f32_16x16x32_f16(a4[ks], b, t, 0, 0, 0);
            }
            float b1v = sb[768 + r];
#pragma unroll
            for (int rr = 0; rr < 4; rr++){
                float hv = gelu_f(t[rr] + b1v);
                int row = g * 4 + rr;
                *(_Float16*)(ab + row * 256 + ((r << 1) ^ ((row & 7) << 4))) = (_Float16)hv;
            }
        }
    }
    __syncthreads();                                            // B9b: hidden tile ready
    {
        load_a(a4, ab, c, g);
        f32x4 accL = (f32x4){0.f,0.f,0.f,0.f};
        const char* rp = (const char*)w2c + c * 256;
        const int swz = (c & 7) << 4;
#pragma unroll
        for (int ks = 0; ks < 4; ks++){
            f16x8 b = *(const f16x8*)(rp + ((ks * 64 + g * 16) ^ swz));
            accL = __builtin_amdgcn_mfma_f32_16x16x32_f16(a4[ks], b, accL, 0, 0, 0);
        }
#pragma unroll
        for (int rr = 0; rr < 4; rr++){
            float lg = accL[rr] + ((c < 2) ? sb[1536 + c] : 0.f);
            float ot = __shfl_xor(lg, 1);
            float mx = fmaxf(lg, ot);
            float lse = mx + logf(expf(lg - mx) + expf(ot - mx));
            ceC[rr] = lse - ((lab == c) ? lg : ot);
        }
    }
    __syncthreads();                                            // B10
    sw_write(s, wbuf, tid);
    __syncthreads();                                            // B11: jd_w1 B-half ready

    // ---------------- joint LN stats; ys pass (frees accS) ------------------
    sw_load(s, jd_w1, tid);   // prefetch jd_w1 A-half (c_rep dims)
    float jm[4], jr[4];
    {
        float s0[4]={0,0,0,0}, s1[4]={0,0,0,0};
#pragma unroll
        for (int n = 0; n < 8; n++)
#pragma unroll
            for (int rr = 0; rr < 4; rr++){
                float v = accC[n][rr]; s0[rr]+=v; s1[rr]+=v*v;
                float u = accS[n][rr]; s0[rr]+=u; s1[rr]+=u*u;
            }
#pragma unroll
        for (int rr = 0; rr < 4; rr++)
#pragma unroll
            for (int m = 1; m < 16; m <<= 1){ s0[rr]+=__shfl_xor(s0[rr],m); s1[rr]+=__shfl_xor(s1[rr],m); }
#pragma unroll
        for (int rr = 0; rr < 4; rr++){
            jm[rr] = s0[rr] * (1.f/256.f);
            jr[rr] = rsqrtf(s1[rr]*(1.f/256.f) - jm[rr]*jm[rr] + 1e-5f);
        }
#pragma unroll
        for (int n = 0; n < 8; n++){
            const int col = n * 16 + c;
#pragma unroll
            for (int rr = 0; rr < 4; rr++){
                float y = (accS[n][rr]-jm[rr])*jr[rr]*sb[1024+128+col] + sb[1280+128+col];
                int row = g * 4 + rr;
                *(_Float16*)(ab + row * 256 + ((col << 1) ^ ((row & 7) << 4))) = (_Float16)y;
            }
        }
    }
    __syncthreads();                                            // B11a: ys tile ready
    {
        load_a(a4, ab, c, g);
#pragma unroll
        for (int n = 0; n < 8; n++) accW2[n] = (f32x4){0.f,0.f,0.f,0.f};
        mfma_tile(accW2, a4, wbuf, c, g);   // ys @ jd_w1[128:256]
    }
    __syncthreads();                                            // B12
    sw_write(s, wbuf, tid);
    __syncthreads();                                            // B13: jd_w1 A-half ready

    // ---------------- yc pass; joint hidden; joint logits; epilogue ---------
    {
        const int rowbase = wrow0 + g * 4;
        const int4  m4 = *(const int4*)(mask + rowbase);
        const float4 e4 = *(const float4*)(ws + (rowbase & 63));
        const float4 s4 = *(const float4*)(ws + 64 + (rowbase & 63));

#pragma unroll
        for (int n = 0; n < 8; n++){
            const int col = n * 16 + c;
#pragma unroll
            for (int rr = 0; rr < 4; rr++){
                float y = (accC[n][rr]-jm[rr])*jr[rr]*sb[1024+col] + sb[1280+col];
                int row = g * 4 + rr;
                *(_Float16*)(ab + row * 256 + ((col << 1) ^ ((row & 7) << 4))) = (_Float16)y;
            }
        }
        __syncthreads();                                        // B13a: yc tile ready
        load_a(a4, ab, c, g);
        mfma_tile(accW2, a4, wbuf, c, g);   // += yc @ jd_w1[0:128]
        // joint hidden -> gelu -> ab
#pragma unroll
        for (int n = 0; n < 8; n++){
            const int r = n * 16 + c;
            float b1v = sb[896 + r];
#pragma unroll
            for (int rr = 0; rr < 4; rr++){
                float hv = gelu_f(accW2[n][rr] + b1v);
                int row = g * 4 + rr;
                *(_Float16*)(ab + row * 256 + ((r << 1) ^ ((row & 7) << 4))) = (_Float16)hv;
            }
        }
        __syncthreads();                                        // B13b: hidden tile ready
        load_a(a4, ab, c, g);
        f32x4 accL = (f32x4){0.f,0.f,0.f,0.f};
        const char* rp = (const char*)w2j + c * 256;
        const int swz = (c & 7) << 4;
#pragma unroll
        for (int ks = 0; ks < 4; ks++){
            f16x8 b = *(const f16x8*)(rp + ((ks * 64 + g * 16) ^ swz));
            accL = __builtin_amdgcn_mfma_f32_16x16x32_f16(a4[ks], b, accL, 0, 0, 0);
        }
#pragma unroll
        for (int rr = 0; rr < 4; rr++){
            float lg = accL[rr] + ((c < 2) ? sb[1538 + c] : 0.f);
            float ot = __shfl_xor(lg, 1);
            float mx = fmaxf(lg, ot);
            float lse = mx + logf(expf(lg - mx) + expf(ot - mx));
            ceJ[rr] = lse - ((lab == c) ? lg : ot);
        }

        if (c == 0){
            const int   mm[4] = {m4.x, m4.y, m4.z, m4.w};
            const float ee[4] = {e4.x, e4.y, e4.z, e4.w};
            const float sv[4] = {s4.x, s4.y, s4.z, s4.w};
            float rw[4], mc[4], mj[4];
#pragma unroll
            for (int rr = 0; rr < 4; rr++){
                float mf = mm[rr] ? 1.f : 0.f;
                float cec = ceC[rr], cej = ceJ[rr];
                rw[rr] = mf * sv[rr] * (ee[rr] - cec - 0.5f * fmaxf(cec - cej, 0.f));
                mc[rr] = mf * cec;
                mj[rr] = mf * cej;
            }
            *(float4*)(out + rowbase)              = (float4){rw[0], rw[1], rw[2], rw[3]};
            *(float4*)(ws + 256 + rowbase)         = (float4){mc[0], mc[1], mc[2], mc[3]};
            *(float4*)(ws + 256 + NROWS + rowbase) = (float4){mj[0], mj[1], mj[2], mj[3]};
        }
    }
}

// ======================= aux reductions ====================================
__global__ void k_aux1(float* __restrict__ ws){
    int t = blockIdx.x, tid = threadIdx.x;
    const float* mc = ws + 256;
    const float* mj = ws + 256 + NROWS;
    float sc = 0.f, sj = 0.f;
    for (int b = tid; b < B_; b += 256){ sc += mc[b * T_ + t]; sj += mj[b * T_ + t]; }
    for (int m = 1; m < 64; m <<= 1){ sc += __shfl_xor(sc, m); sj += __shfl_xor(sj, m); }
    __shared__ float sh[8];
    int w = tid >> 6, l = tid & 63;
    if (l == 0){ sh[w] = sc; sh[4 + w] = sj; }
    __syncthreads();
    if (tid == 0){
        float a0 = sh[0] + sh[1] + sh[2] + sh[3];
        float a1 = sh[4] + sh[5] + sh[6] + sh[7];
        ws[192 + t] = ws[64 + t] * 0.5f * (a0 + a1) / fmaxf(ws[128 + t], 1.f);
    }
}

__global__ void k_aux2(const float* __restrict__ ws, float* __restrict__ out){
    int l = threadIdx.x;
    float cv = ws[192 + l], sv = ws[64 + l];
    for (int m = 1; m < 64; m <<= 1){ cv += __shfl_xor(cv, m); sv += __shfl_xor(sv, m); }
    if (l == 0) out[NROWS] = (sv > 0.f) ? cv / fmaxf(sv, 1.f) : 0.f;
}

extern "C" void kernel_launch(void* const* d_in, const int* in_sizes, int n_in,
                              void* d_out, int out_size, void* d_ws, size_t ws_size,
                              hipStream_t stream) {
    const float* xc     = (const float*)d_in[0];
    const float* xs     = (const float*)d_in[1];
    const int*   labels = (const int*)d_in[2];
    const int*   mask   = (const int*)d_in[3];
    const float* ce_w1  = (const float*)d_in[4];
    const float* ce_b1  = (const float*)d_in[5];
    const float* ce_w2  = (const float*)d_in[6];
    const float* ce_b2  = (const float*)d_in[7];
    const float* se_w1  = (const float*)d_in[8];
    const float* se_b1  = (const float*)d_in[9];
    const float* se_w2  = (const float*)d_in[10];
    const float* se_b2  = (const float*)d_in[11];
    const float* cd_g   = (const float*)d_in[12];
    const float* cd_b   = (const float*)d_in[13];
    const float* cd_w1  = (const float*)d_in[14];
    const float* cd_b1  = (const float*)d_in[15];
    const float* cd_w2  = (const float*)d_in[16];
    const float* cd_b2  = (const float*)d_in[17];
    const float* jd_g   = (const float*)d_in[18];
    const float* jd_b   = (const float*)d_in[19];
    const float* jd_w1  = (const float*)d_in[20];
    const float* jd_b1  = (const float*)d_in[21];
    const float* jd_w2  = (const float*)d_in[22];
    const float* jd_b2  = (const float*)d_in[23];
    float* ws  = (float*)d_ws;
    float* out = (float*)d_out;

    k_stats<<<64, 256, 0, stream>>>(mask, labels, ws);
    k_main<<<2048, 512, 0, stream>>>(xc, xs, labels, mask,
                                     ce_w1, ce_b1, ce_w2, ce_b2,
                                     se_w1, se_b1, se_w2, se_b2,
                                     cd_g, cd_b, cd_w1, cd_b1, cd_w2, cd_b2,
                                     jd_g, jd_b, jd_w1, jd_b1, jd_w2, jd_b2,
                                     ws, out);
    k_aux1<<<64, 256, 0, stream>>>(ws);
    k_aux2<<<1, 64, 0, stream>>>(ws, out);
}

// Round 4
// 361.822 us; speedup vs baseline: 1.7877x; 1.7877x over previous
//
#include <hip/hip_runtime.h>
#include <hip/hip_fp16.h>

#define B_ 4096
#define T_ 64
#define NROWS (B_*T_)   // 262144

typedef _Float16 f16x8 __attribute__((ext_vector_type(8)));
typedef float    f32x4 __attribute__((ext_vector_type(4)));

__device__ __forceinline__ float gelu_f(float x){
    return 0.5f * x * (1.0f + erff(x * 0.70710678118654752f));
}

// ---------- staged-weight pipeline: [128][128] f32 -> 16 VGPRs f16 -> 4x ds_write_b128
// Layout: WT[cc][k] at byte cc*256 + ((2k) ^ ((cc&7)<<4))
struct SW { f16x8 v[4]; };

__device__ __forceinline__ void sw_load(SW& s, const float* __restrict__ w, int tid){
    const int l = tid & 63, kk0 = (tid >> 6) & 7;
#pragma unroll
    for (int hh = 0; hh < 2; hh++){
        const int cc = l + hh * 64;
#pragma unroll
        for (int j = 0; j < 2; j++){
            const int kk = kk0 + j * 8;
            const float* src = w + kk * 8 * 128 + cc;   // 64 lanes: 256B coalesced
            f16x8 t;
#pragma unroll
            for (int m = 0; m < 8; m++) t[m] = (_Float16)src[m * 128];
            s.v[hh * 2 + j] = t;
        }
    }
}

__device__ __forceinline__ void sw_write(const SW& s, unsigned short* buf, int tid){
    const int l = tid & 63, kk0 = (tid >> 6) & 7;
#pragma unroll
    for (int hh = 0; hh < 2; hh++){
        const int cc = l + hh * 64;
        char* dst = (char*)buf + cc * 256;
        const int swz = (cc & 7) << 4;
#pragma unroll
        for (int j = 0; j < 2; j++){
            const int kk = kk0 + j * 8;
            *(f16x8*)(dst + ((kk * 16) ^ swz)) = s.v[hh * 2 + j];
        }
    }
}

// ---------- stage W2 (128 x 2) transposed+padded to WT[16][128] (rows 2..15 zero)
__device__ __forceinline__ void stage_w2(const float* __restrict__ w,
                                         unsigned short* buf, int tid){
    for (int idx = tid; idx < 2048; idx += 512){
        int r = idx >> 7, k = idx & 127;
        float v = (r < 2) ? w[k * 2 + r] : 0.f;
        int byte = r * 256 + ((k << 1) ^ ((r & 7) << 4));
        *(_Float16*)((char*)buf + byte) = (_Float16)v;
    }
}

// ---------- input rows -> f16 A-fragments (K=128 -> 4 frags)
__device__ __forceinline__ void load_in(f16x8* a, const float* __restrict__ p, int g){
#pragma unroll
    for (int ks = 0; ks < 4; ks++){
        const float* q = p + ks * 32 + g * 8;
        float4 v0 = *(const float4*)q, v1 = *(const float4*)(q + 4);
        f16x8 t;
        t[0]=(_Float16)v0.x; t[1]=(_Float16)v0.y; t[2]=(_Float16)v0.z; t[3]=(_Float16)v0.w;
        t[4]=(_Float16)v1.x; t[5]=(_Float16)v1.y; t[6]=(_Float16)v1.z; t[7]=(_Float16)v1.w;
        a[ks] = t;
    }
}

// ---------- A-fragments from wave-private abuf tile [16][128] f16
__device__ __forceinline__ void load_a(f16x8* a, const char* ab, int c, int g){
    const int rswz = (c & 7) << 4;
    const char* rp = ab + c * 256;
#pragma unroll
    for (int ks = 0; ks < 4; ks++)
        a[ks] = *(const f16x8*)(rp + ((ks * 64 + g * 16) ^ rswz));
}

// ---------- full 8-tile MFMA vs staged weights (K=128, row stride 256B)
__device__ __forceinline__ void mfma_tile(f32x4* acc, const f16x8* a,
                                          const unsigned short* wb, int c, int g){
#pragma unroll
    for (int n = 0; n < 8; n++){
        const int r = n * 16 + c;
        const char* rp = (const char*)wb + r * 256;
        const int swz = (r & 7) << 4;
#pragma unroll
        for (int ks = 0; ks < 4; ks++){
            f16x8 b = *(const f16x8*)(rp + ((ks * 64 + g * 16) ^ swz));
            acc[n] = __builtin_amdgcn_mfma_f32_16x16x32_f16(a[ks], b, acc[n], 0, 0, 0);
        }
    }
}

// ======================= stats kernel ======================================
__global__ void k_stats(const int* __restrict__ mask, const int* __restrict__ labels,
                        float* __restrict__ ws){
    int t = blockIdx.x, tid = threadIdx.x;
    float c0 = 0.f, c1 = 0.f;
    for (int b = tid; b < B_; b += 256){
        if (mask[b * T_ + t]){
            if (labels[b] == 1) c1 += 1.f; else c0 += 1.f;
        }
    }
    for (int m = 1; m < 64; m <<= 1){ c0 += __shfl_xor(c0, m); c1 += __shfl_xor(c1, m); }
    __shared__ float sh[8];
    int w = tid >> 6, l = tid & 63;
    if (l == 0){ sh[w] = c0; sh[4 + w] = c1; }
    __syncthreads();
    if (tid == 0){
        float a0 = sh[0] + sh[1] + sh[2] + sh[3];
        float a1 = sh[4] + sh[5] + sh[6] + sh[7];
        float tot = a0 + a1;
        float d = fmaxf(tot, 1.f);
        float p0 = a0 / d, p1 = a1 / d;
        float ent = -(p0 * logf(p0 + 1e-8f) + p1 * logf(p1 + 1e-8f));
        ws[t] = ent;
        ws[64 + t] = (tot >= 2.f) ? 1.f : 0.f;
        ws[128 + t] = tot;
    }
}

// ======================= prep kernel: qv = jd_g[:128]@W1A, bv = jd_b[:128]@W1A
__global__ void k_prep(const float* __restrict__ jd_g, const float* __restrict__ jd_b,
                       const float* __restrict__ jd_w1, float* __restrict__ ws){
    int j = threadIdx.x;   // 128 threads
    float q = 0.f, bb = 0.f;
    for (int k = 0; k < 128; k++){
        float w = jd_w1[k * 128 + j];
        q  += jd_g[k] * w;
        bb += jd_b[k] * w;
    }
    ws[256 + j] = q;
    ws[384 + j] = bb;
}

// ======================= main fused kernel =================================
// LDS: wbuf 32K + abuf 32K + w2c 4K + w2j 4K + sb 6.7K = 78.7 KB -> 2 blocks/CU
// if VGPR <= 128. launch_bounds(512,2) empirically yields exactly 128 (R1).
__global__ __launch_bounds__(512, 2) void k_main(
    const float* __restrict__ xc, const float* __restrict__ xs,
    const int* __restrict__ labels, const int* __restrict__ mask,
    const float* __restrict__ ce_w1, const float* __restrict__ ce_b1,
    const float* __restrict__ ce_w2, const float* __restrict__ ce_b2,
    const float* __restrict__ se_w1, const float* __restrict__ se_b1,
    const float* __restrict__ se_w2, const float* __restrict__ se_b2,
    const float* __restrict__ cd_g,  const float* __restrict__ cd_bt,
    const float* __restrict__ cd_w1, const float* __restrict__ cd_b1,
    const float* __restrict__ cd_w2, const float* __restrict__ cd_b2,
    const float* __restrict__ jd_g,  const float* __restrict__ jd_bt,
    const float* __restrict__ jd_w1, const float* __restrict__ jd_b1,
    const float* __restrict__ jd_w2, const float* __restrict__ jd_b2,
    float* __restrict__ ws, float* __restrict__ out)
{
    __shared__ __align__(16) unsigned short wbuf[128 * 128];    // 32 KB
    __shared__ __align__(16) unsigned short abuf[8 * 16 * 128]; // 32 KB
    __shared__ __align__(16) unsigned short w2c[16 * 128];      // 4 KB
    __shared__ __align__(16) unsigned short w2j[16 * 128];      // 4 KB
    __shared__ float sb[1668];
    // sb: 0 ce_b1 |128 ce_b2 |256 se_b1 |384 se_b2 |512 cd_g |640 cd_b |768 cd_b1
    //     896 jd_b1 |1024 jd_gB |1152 jd_bB |1280 qv |1408 bv |1536 jd_gA
    //     1664 cd_b2[2] |1666 jd_b2[2]

    const int tid = threadIdx.x;
    const int wave = tid >> 6, lane = tid & 63;
    const int c = lane & 15, g = lane >> 4;
    const int wrow0 = blockIdx.x * 128 + wave * 16;
    char* const ab = (char*)abuf + wave * 4096;
    const int lab = labels[(wrow0 + g * 4) >> 6];

    SW s;
    f16x8 a4[4];
    f32x4 accC[8], accU[8];
    float s0c[4], s1c[4];
    float jm[4], jr[4];
    float ceC[4], ceJ[4];

    // ---------------- P0: stage ce_w1 + w2 pads + sb; hoist xc ------------
    sw_load(s, ce_w1, tid);
    f16x8 aC[4];
    load_in(aC, xc + (wrow0 + c) * 128, g);
    stage_w2(cd_w2, w2c, tid);
    stage_w2(jd_w2, w2j, tid);
    if (tid < 128){
        sb[tid] = ce_b1[tid];       sb[128 + tid] = ce_b2[tid];
        sb[256 + tid] = se_b1[tid]; sb[384 + tid] = se_b2[tid];
        sb[512 + tid] = cd_g[tid];  sb[640 + tid] = cd_bt[tid];
        sb[768 + tid] = cd_b1[tid]; sb[896 + tid] = jd_b1[tid];
    } else if (tid < 256){
        int i = tid - 128;
        sb[1024 + i] = jd_g[128 + i]; sb[1152 + i] = jd_bt[128 + i];
        sb[1280 + i] = ws[256 + i];   sb[1408 + i] = ws[384 + i];
        sb[1536 + i] = jd_g[i];
    } else if (tid < 258){
        int i = tid - 256; sb[1664 + i] = cd_b2[i]; sb[1666 + i] = jd_b2[i];
    }
    sw_write(s, wbuf, tid);
    __syncthreads();                                            // S1: ce_w1 ready

    // ---------------- P1: enc1 causal (wbuf=ce_w1) -------------------------
    sw_load(s, ce_w2, tid);
    {
        f32x4 acc[8];
#pragma unroll
        for (int n = 0; n < 8; n++) acc[n] = (f32x4){0.f,0.f,0.f,0.f};
        mfma_tile(acc, aC, wbuf, c, g);
#pragma unroll
        for (int n = 0; n < 8; n++){
            const int col = n * 16 + c;
            float bi = sb[col];
#pragma unroll
            for (int rr = 0; rr < 4; rr++){
                float v = gelu_f(acc[n][rr] + bi);
                int row = g * 4 + rr;
                *(_Float16*)(ab + row * 256 + ((col << 1) ^ ((row & 7) << 4))) = (_Float16)v;
            }
        }
    }
    __syncthreads();                                            // S2
    sw_write(s, wbuf, tid);
    __syncthreads();                                            // S3: ce_w2 ready

    // ---------------- P2: enc2 causal -> accC; sums; u_in -> ab ------------
    sw_load(s, jd_w1, tid);          // jd_w1 A-half (rows 0..127)
    {
        load_a(a4, ab, c, g);
#pragma unroll
        for (int n = 0; n < 8; n++) accC[n] = (f32x4){0.f,0.f,0.f,0.f};
        mfma_tile(accC, a4, wbuf, c, g);
#pragma unroll
        for (int n = 0; n < 8; n++){
            float bi = sb[128 + n * 16 + c];
#pragma unroll
            for (int rr = 0; rr < 4; rr++) accC[n][rr] += bi;
        }
#pragma unroll
        for (int rr = 0; rr < 4; rr++){ s0c[rr] = 0.f; s1c[rr] = 0.f; }
#pragma unroll
        for (int n = 0; n < 8; n++)
#pragma unroll
            for (int rr = 0; rr < 4; rr++){ float v = accC[n][rr]; s0c[rr]+=v; s1c[rr]+=v*v; }
#pragma unroll
        for (int rr = 0; rr < 4; rr++)
#pragma unroll
            for (int m = 1; m < 16; m <<= 1){ s0c[rr]+=__shfl_xor(s0c[rr],m); s1c[rr]+=__shfl_xor(s1c[rr],m); }
        // u_in = c_rep * jd_gA -> ab (f16)
#pragma unroll
        for (int n = 0; n < 8; n++){
            const int col = n * 16 + c;
            float gA = sb[1536 + col];
#pragma unroll
            for (int rr = 0; rr < 4; rr++){
                int row = g * 4 + rr;
                *(_Float16*)(ab + row * 256 + ((col << 1) ^ ((row & 7) << 4))) = (_Float16)(accC[n][rr] * gA);
            }
        }
    }
    __syncthreads();                                            // S4
    sw_write(s, wbuf, tid);
    __syncthreads();                                            // S5: jd_w1A ready, ab=u_in

    // ---------------- P3: U = u_in @ jd_w1A; causal LN -> ab ---------------
    sw_load(s, cd_w1, tid);
    {
        load_a(a4, ab, c, g);       // u_in (read before overwriting ab)
        // causal LN write (frees accC before the MFMA burst)
        float mc[4], rc[4];
#pragma unroll
        for (int rr = 0; rr < 4; rr++){
            mc[rr] = s0c[rr] * (1.f/128.f);
            rc[rr] = rsqrtf(s1c[rr]*(1.f/128.f) - mc[rr]*mc[rr] + 1e-5f);
        }
#pragma unroll
        for (int n = 0; n < 8; n++){
            const int col = n * 16 + c;
#pragma unroll
            for (int rr = 0; rr < 4; rr++){
                float y = (accC[n][rr]-mc[rr])*rc[rr]*sb[512+col] + sb[640+col];
                int row = g * 4 + rr;
                *(_Float16*)(ab + row * 256 + ((col << 1) ^ ((row & 7) << 4))) = (_Float16)y;
            }
        }
#pragma unroll
        for (int n = 0; n < 8; n++) accU[n] = (f32x4){0.f,0.f,0.f,0.f};
        mfma_tile(accU, a4, wbuf, c, g);    // U
    }
    __syncthreads();                                            // S6
    sw_write(s, wbuf, tid);
    __syncthreads();                                            // S7: cd_w1 ready, ab=LN-c

    // ---------------- P4: dec-c hidden -> ab; logits -> ceC ----------------
    sw_load(s, se_w1, tid);
    f16x8 aS[4];
    load_in(aS, xs + (wrow0 + c) * 128, g);
    {
        load_a(a4, ab, c, g);
#pragma unroll
        for (int n = 0; n < 8; n++){
            const int r = n * 16 + c;
            const char* rp = (const char*)wbuf + r * 256;
            const int swz = (r & 7) << 4;
            f32x4 t = (f32x4){0.f,0.f,0.f,0.f};
#pragma unroll
            for (int ks = 0; ks < 4; ks++){
                f16x8 b = *(const f16x8*)(rp + ((ks * 64 + g * 16) ^ swz));
                t = __builtin_amdgcn_mfma_f32_16x16x32_f16(a4[ks], b, t, 0, 0, 0);
            }
            float b1v = sb[768 + r];
#pragma unroll
            for (int rr = 0; rr < 4; rr++){
                float hv = gelu_f(t[rr] + b1v);
                int row = g * 4 + rr;
                *(_Float16*)(ab + row * 256 + ((r << 1) ^ ((row & 7) << 4))) = (_Float16)hv;
            }
        }
    }
    __syncthreads();                                            // S8: hidden ready, wbuf free
    sw_write(s, wbuf, tid);     // wbuf <- se_w1 (concurrent with logits below)
    {
        load_a(a4, ab, c, g);
        f32x4 accL = (f32x4){0.f,0.f,0.f,0.f};
        const char* rp = (const char*)w2c + c * 256;
        const int swz = (c & 7) << 4;
#pragma unroll
        for (int ks = 0; ks < 4; ks++){
            f16x8 b = *(const f16x8*)(rp + ((ks * 64 + g * 16) ^ swz));
            accL = __builtin_amdgcn_mfma_f32_16x16x32_f16(a4[ks], b, accL, 0, 0, 0);
        }
#pragma unroll
        for (int rr = 0; rr < 4; rr++){
            float lg = accL[rr] + ((c < 2) ? sb[1664 + c] : 0.f);
            float ot = __shfl_xor(lg, 1);
            float mx = fmaxf(lg, ot);
            float lse = mx + logf(expf(lg - mx) + expf(ot - mx));
            ceC[rr] = lse - ((lab == c) ? lg : ot);
        }
    }
    __syncthreads();                                            // S9: se_w1 ready

    // ---------------- P5: enc1 spurious ------------------------------------
    sw_load(s, se_w2, tid);
    {
        f32x4 acc[8];
#pragma unroll
        for (int n = 0; n < 8; n++) acc[n] = (f32x4){0.f,0.f,0.f,0.f};
        mfma_tile(acc, aS, wbuf, c, g);
#pragma unroll
        for (int n = 0; n < 8; n++){
            const int col = n * 16 + c;
            float bi = sb[256 + col];
#pragma unroll
            for (int rr = 0; rr < 4; rr++){
                float v = gelu_f(acc[n][rr] + bi);
                int row = g * 4 + rr;
                *(_Float16*)(ab + row * 256 + ((col << 1) ^ ((row & 7) << 4))) = (_Float16)v;
            }
        }
    }
    __syncthreads();                                            // S10
    sw_write(s, wbuf, tid);
    __syncthreads();                                            // S11: se_w2 ready

    // ---------------- P6: enc2 spurious; joint LN; ys -> ab ----------------
    {
        f32x4 accS[8];
        load_a(a4, ab, c, g);
#pragma unroll
        for (int n = 0; n < 8; n++) accS[n] = (f32x4){0.f,0.f,0.f,0.f};
        mfma_tile(accS, a4, wbuf, c, g);
#pragma unroll
        for (int n = 0; n < 8; n++){
            float bi = sb[384 + n * 16 + c];
#pragma unroll
            for (int rr = 0; rr < 4; rr++) accS[n][rr] += bi;
        }
        float s0s[4]={0,0,0,0}, s1s[4]={0,0,0,0};
#pragma unroll
        for (int n = 0; n < 8; n++)
#pragma unroll
            for (int rr = 0; rr < 4; rr++){ float u = accS[n][rr]; s0s[rr]+=u; s1s[rr]+=u*u; }
#pragma unroll
        for (int rr = 0; rr < 4; rr++)
#pragma unroll
            for (int m = 1; m < 16; m <<= 1){ s0s[rr]+=__shfl_xor(s0s[rr],m); s1s[rr]+=__shfl_xor(s1s[rr],m); }
#pragma unroll
        for (int rr = 0; rr < 4; rr++){
            float s0 = s0c[rr] + s0s[rr], s1 = s1c[rr] + s1s[rr];
            jm[rr] = s0 * (1.f/256.f);
            jr[rr] = rsqrtf(s1*(1.f/256.f) - jm[rr]*jm[rr] + 1e-5f);
        }
        sw_load(s, jd_w1 + 128 * 128, tid);   // B-half prefetch (sums regs now dead)
#pragma unroll
        for (int n = 0; n < 8; n++){
            const int col = n * 16 + c;
#pragma unroll
            for (int rr = 0; rr < 4; rr++){
                float y = (accS[n][rr]-jm[rr])*jr[rr]*sb[1024+col] + sb[1152+col];
                int row = g * 4 + rr;
                *(_Float16*)(ab + row * 256 + ((col << 1) ^ ((row & 7) << 4))) = (_Float16)y;
            }
        }
    }
    __syncthreads();                                            // S12
    sw_write(s, wbuf, tid);
    __syncthreads();                                            // S13: jd_w1B ready, ab=ys

    // ---------------- P7: joint hidden (fold U); logits; epilogue ----------
    {
        const int rowbase = wrow0 + g * 4;
        const int4  m4 = *(const int4*)(mask + rowbase);
        const float4 e4 = *(const float4*)(ws + (rowbase & 63));
        const float4 s4 = *(const float4*)(ws + 64 + (rowbase & 63));

        load_a(a4, ab, c, g);       // ys
        f32x4 accJ[8];
#pragma unroll
        for (int n = 0; n < 8; n++) accJ[n] = (f32x4){0.f,0.f,0.f,0.f};
        mfma_tile(accJ, a4, wbuf, c, g);    // ys @ jd_w1B
        // hidden_in = accJ + jr*U + bv - jm*jr*qv + jd_b1 ; gelu -> ab
#pragma unroll
        for (int n = 0; n < 8; n++){
            const int col = n * 16 + c;
            float qvv = sb[1280 + col], bvv = sb[1408 + col], b1v = sb[896 + col];
#pragma unroll
            for (int rr = 0; rr < 4; rr++){
                float hin = accJ[n][rr] + jr[rr]*accU[n][rr] + bvv - jm[rr]*jr[rr]*qvv + b1v;
                float hv = gelu_f(hin);
                int row = g * 4 + rr;
                *(_Float16*)(ab + row * 256 + ((col << 1) ^ ((row & 7) << 4))) = (_Float16)hv;
            }
        }
    }
    __syncthreads();                                            // S14: hidden_j ready
    {
        load_a(a4, ab, c, g);
        f32x4 accL = (f32x4){0.f,0.f,0.f,0.f};
        const char* rp = (const char*)w2j + c * 256;
        const int swz = (c & 7) << 4;
#pragma unroll
        for (int ks = 0; ks < 4; ks++){
            f16x8 b = *(const f16x8*)(rp + ((ks * 64 + g * 16) ^ swz));
            accL = __builtin_amdgcn_mfma_f32_16x16x32_f16(a4[ks], b, accL, 0, 0, 0);
        }
#pragma unroll
        for (int rr = 0; rr < 4; rr++){
            float lg = accL[rr] + ((c < 2) ? sb[1666 + c] : 0.f);
            float ot = __shfl_xor(lg, 1);
            float mx = fmaxf(lg, ot);
            float lse = mx + logf(expf(lg - mx) + expf(ot - mx));
            ceJ[rr] = lse - ((lab == c) ? lg : ot);
        }

        if (c == 0){
            const int rowbase = wrow0 + g * 4;
            const int4  m4 = *(const int4*)(mask + rowbase);
            const float4 e4 = *(const float4*)(ws + (rowbase & 63));
            const float4 s4 = *(const float4*)(ws + 64 + (rowbase & 63));
            const int   mm[4] = {m4.x, m4.y, m4.z, m4.w};
            const float ee[4] = {e4.x, e4.y, e4.z, e4.w};
            const float sv[4] = {s4.x, s4.y, s4.z, s4.w};
            float rw[4], mc2[4], mj2[4];
#pragma unroll
            for (int rr = 0; rr < 4; rr++){
                float mf = mm[rr] ? 1.f : 0.f;
                float cec = ceC[rr], cej = ceJ[rr];
                rw[rr]  = mf * sv[rr] * (ee[rr] - cec - 0.5f * fmaxf(cec - cej, 0.f));
                mc2[rr] = mf * cec;
                mj2[rr] = mf * cej;
            }
            *(float4*)(out + rowbase)              = (float4){rw[0], rw[1], rw[2], rw[3]};
            *(float4*)(ws + 512 + rowbase)         = (float4){mc2[0], mc2[1], mc2[2], mc2[3]};
            *(float4*)(ws + 512 + NROWS + rowbase) = (float4){mj2[0], mj2[1], mj2[2], mj2[3]};
        }
    }
}

// ======================= aux reductions ====================================
__global__ void k_aux1(float* __restrict__ ws){
    int t = blockIdx.x, tid = threadIdx.x;
    const float* mc = ws + 512;
    const float* mj = ws + 512 + NROWS;
    float sc = 0.f, sj = 0.f;
    for (int b = tid; b < B_; b += 256){ sc += mc[b * T_ + t]; sj += mj[b * T_ + t]; }
    for (int m = 1; m < 64; m <<= 1){ sc += __shfl_xor(sc, m); sj += __shfl_xor(sj, m); }
    __shared__ float sh[8];
    int w = tid >> 6, l = tid & 63;
    if (l == 0){ sh[w] = sc; sh[4 + w] = sj; }
    __syncthreads();
    if (tid == 0){
        float a0 = sh[0] + sh[1] + sh[2] + sh[3];
        float a1 = sh[4] + sh[5] + sh[6] + sh[7];
        ws[192 + t] = ws[64 + t] * 0.5f * (a0 + a1) / fmaxf(ws[128 + t], 1.f);
    }
}

__global__ void k_aux2(const float* __restrict__ ws, float* __restrict__ out){
    int l = threadIdx.x;
    float cv = ws[192 + l], sv = ws[64 + l];
    for (int m = 1; m < 64; m <<= 1){ cv += __shfl_xor(cv, m); sv += __shfl_xor(sv, m); }
    if (l == 0) out[NROWS] = (sv > 0.f) ? cv / fmaxf(sv, 1.f) : 0.f;
}

extern "C" void kernel_launch(void* const* d_in, const int* in_sizes, int n_in,
                              void* d_out, int out_size, void* d_ws, size_t ws_size,
                              hipStream_t stream) {
    const float* xc     = (const float*)d_in[0];
    const float* xs     = (const float*)d_in[1];
    const int*   labels = (const int*)d_in[2];
    const int*   mask   = (const int*)d_in[3];
    const float* ce_w1  = (const float*)d_in[4];
    const float* ce_b1  = (const float*)d_in[5];
    const float* ce_w2  = (const float*)d_in[6];
    const float* ce_b2  = (const float*)d_in[7];
    const float* se_w1  = (const float*)d_in[8];
    const float* se_b1  = (const float*)d_in[9];
    const float* se_w2  = (const float*)d_in[10];
    const float* se_b2  = (const float*)d_in[11];
    const float* cd_g   = (const float*)d_in[12];
    const float* cd_b   = (const float*)d_in[13];
    const float* cd_w1  = (const float*)d_in[14];
    const float* cd_b1  = (const float*)d_in[15];
    const float* cd_w2  = (const float*)d_in[16];
    const float* cd_b2  = (const float*)d_in[17];
    const float* jd_g   = (const float*)d_in[18];
    const float* jd_b   = (const float*)d_in[19];
    const float* jd_w1  = (const float*)d_in[20];
    const float* jd_b1  = (const float*)d_in[21];
    const float* jd_w2  = (const float*)d_in[22];
    const float* jd_b2  = (const float*)d_in[23];
    float* ws  = (float*)d_ws;
    float* out = (float*)d_out;

    k_stats<<<64, 256, 0, stream>>>(mask, labels, ws);
    k_prep<<<1, 128, 0, stream>>>(jd_g, jd_b, jd_w1, ws);
    k_main<<<2048, 512, 0, stream>>>(xc, xs, labels, mask,
                                     ce_w1, ce_b1, ce_w2, ce_b2,
                                     se_w1, se_b1, se_w2, se_b2,
                                     cd_g, cd_b, cd_w1, cd_b1, cd_w2, cd_b2,
                                     jd_g, jd_b, jd_w1, jd_b1, jd_w2, jd_b2,
                                     ws, out);
    k_aux1<<<64, 256, 0, stream>>>(ws);
    k_aux2<<<1, 64, 0, stream>>>(ws, out);
}